// Round 5
// baseline (303.472 us; speedup 1.0000x reference)
//
#include <hip/hip_runtime.h>

// TileWarping: B=4, C=16, H=512, W=960, UP=4 -> out [4, 48, 128, 240] f32.
// R4: direct-gather with EXPLICIT load/consume phase split.
// R0-R3 post-mortem: all rounds latency-bound (every pipe <20%) because the
// compiler emitted minimal-VGPR serial chains (VGPR_Count 28-64): per channel,
// issue ~5 loads -> waitcnt -> consume. 16 sequential gather latencies/thread.
// Fix: load ALL 80 values (4 taps + fea_l, x16 channels) into register arrays
// first (80 independent loads in flight), then reduce. ~110 VGPRs;
// __launch_bounds__(320,4) caps at 128 VGPRs, 3 blocks/CU = 15 waves/CU.
// k-trick kept: 3 disp_d variants share taps p..p+3; OOB handled by clamped
// addresses + zero-masked channel-invariant weights. No LDS, no barriers.

#define NB 4
#define NC 16
#define NH 512
#define NW 960
#define TH 128
#define TW 240
#define HW (NH * NW)

__global__ __launch_bounds__(320, 4) void tile_warp_kernel(
    const float* __restrict__ tp,   // [B,3,128,240]
    const float* __restrict__ fl,   // [B,16,512,960]
    const float* __restrict__ fr,   // [B,16,512,960]
    float* __restrict__ out)        // [B,48,128,240]
{
    const int t = threadIdx.x;      // 0..319
    const int s = blockIdx.x;       // 0..2
    const int Y = blockIdx.y;       // 0..511
    const int b = blockIdx.z;       // 0..3
    const int X = s * 320 + t;      // 0..959
    const int y = Y >> 2, i = Y & 3;
    const int j = X & 3, T = X >> 2;

    // per-thread warp geometry
    const int tpb = (b * 3 * TH + y) * TW + T;
    const float d   = tp[tpb];
    const float dxv = tp[tpb + TH * TW];
    const float dyv = tp[tpb + 2 * TH * TW];
    const float disp = d + ((float)i - 1.5f) * dyv + ((float)j - 1.5f) * dxv;
    const float xf  = (float)X - disp;         // disp_d = 0 variant
    const float x0f = floorf(xf);
    const float w1  = xf - x0f;
    const float w0  = 1.0f - w1;
    const int   p   = (int)x0f - 1;            // shared taps p..p+3

    const int t0 = min(max(p,     0), NW - 1);
    const int t1 = min(max(p + 1, 0), NW - 1);
    const int t2 = min(max(p + 2, 0), NW - 1);
    const int t3 = min(max(p + 3, 0), NW - 1);

    // channel-invariant masked weights for the 3 disp_d variants
    float w0k[3], w1k[3];
#pragma unroll
    for (int kk = 0; kk < 3; ++kk) {
        const int xa = p + 2 - kk;
        const int xb = xa + 1;
        w0k[kk] = (xa >= 0 && xa < NW) ? w0 : 0.0f;
        w1k[kk] = (xb >= 0 && xb < NW) ? w1 : 0.0f;
    }

    const float* frr = fr + (size_t)(b * NC) * HW + (size_t)Y * NW;
    const float* flr = fl + (size_t)(b * NC) * HW + (size_t)Y * NW + X;

    // ---- PHASE 1: issue all 80 loads, no consumption ----
    float m0v[NC], m1v[NC], m2v[NC], m3v[NC], flv[NC];
#pragma unroll
    for (int c = 0; c < NC; ++c) {
        const float* R = frr + (size_t)c * HW;
        m0v[c] = R[t0];
        m1v[c] = R[t1];
        m2v[c] = R[t2];
        m3v[c] = R[t3];
        flv[c] = flr[(size_t)c * HW];
    }

    // ---- PHASE 2: pure-VALU reduction ----
    float a0 = 0.f, a1 = 0.f, a2 = 0.f;
#pragma unroll
    for (int c = 0; c < NC; ++c) {
        a0 += fabsf(flv[c] - (m2v[c] * w0k[0] + m3v[c] * w1k[0]));
        a1 += fabsf(flv[c] - (m1v[c] * w0k[1] + m2v[c] * w1k[1]));
        a2 += fabsf(flv[c] - (m0v[c] * w0k[2] + m1v[c] * w1k[2]));
    }

    const size_t ob = ((size_t)(b * 48 + i * 4 + j) * TH + y) * TW + T;
    out[ob]                        = a0;
    out[ob + 16 * (size_t)TH * TW] = a1;
    out[ob + 32 * (size_t)TH * TW] = a2;
}

extern "C" void kernel_launch(void* const* d_in, const int* in_sizes, int n_in,
                              void* d_out, int out_size, void* d_ws, size_t ws_size,
                              hipStream_t stream) {
    const float* tp = (const float*)d_in[0];
    const float* fl = (const float*)d_in[1];
    const float* fr = (const float*)d_in[2];
    float* out = (float*)d_out;

    dim3 grid(3, NH, NB);   // 6144 blocks
    dim3 block(320);        // 5 waves, all threads active
    tile_warp_kernel<<<grid, block, 0, stream>>>(tp, fl, fr, out);
}